// Round 5
// baseline (199.735 us; speedup 1.0000x reference)
//
#include <hip/hip_runtime.h>

// ChannelAttentionBlock: per batch b, F = x[b] viewed as [4096,128] (row-major).
// S = F F^T ; P = softmax rows ; out[b] = F^T P -> [128, 4096].
//
// k0a cab_cast     : Fbb[b][n][d] = bf16(x)
// k0b cab_transpose: Ftb[b][d][n] = bf16(x)
// k0c cab_norms    : nrm[b][n] = ||bf16 F_n||, mxf[b] = max_n nrm
// k1  cab_rowstats : zpart[mh][b][n] = sum_m 2^(S*L2E - shift_n), shift = nrm*mx*L2E
//                    (Cauchy-Schwarz bound as softmax shift: no online max needed)
// k1b cab_c2       : c2[n] = -(shift_n + log2(z0+z1))
// k2  cab_out      : recompute S, W = 2^(S*L2E + c2) (wave-private LDS), O += F^T W
//
// S bytes/chain order identical in k1/k2. LDS tiles: linear rows, 16B-chunk XOR
// swizzle (chunk ^ (row & (nchunks-1))) applied on gload SOURCE and on read.
// Wide-wave structure: wave owns 32x32 output of each GEMM, B-operands in regs,
// one barrier per K-step, wave-private W (no barrier between G1 and G2).

typedef __attribute__((ext_vector_type(8))) __bf16 bf16x8;
typedef __attribute__((ext_vector_type(4))) float f32x4;
typedef __attribute__((ext_vector_type(4))) unsigned int u32x4;

#define MFMA16(a, b, c) __builtin_amdgcn_mfma_f32_16x16x32_bf16((a), (b), (c), 0, 0, 0)
#define GLOAD16(g, l)                                                       \
  __builtin_amdgcn_global_load_lds(                                         \
      (const __attribute__((address_space(1))) void*)(g),                   \
      (__attribute__((address_space(3))) void*)(l), 16, 0, 0)
#define GLOAD4(g, l)                                                        \
  __builtin_amdgcn_global_load_lds(                                         \
      (const __attribute__((address_space(1))) void*)(g),                   \
      (__attribute__((address_space(3))) void*)(l), 4, 0, 0)

static constexpr int NT = 4096;
static constexpr int DD = 128;
static constexpr float L2E = 1.4426950408889634f;

__device__ __forceinline__ unsigned short bfc(float f) {
  return __builtin_bit_cast(unsigned short, (__bf16)f);
}

// ---------------------------------------------------------------------------
// k0a: row-major cast. grid 2048.
// ---------------------------------------------------------------------------
__global__ __launch_bounds__(256) void cab_cast(const float* __restrict__ x,
                                                ushort* __restrict__ Fbb) {
  size_t i = ((size_t)blockIdx.x * 256 + threadIdx.x) * 8;
  float4 a = *(const float4*)(x + i);
  float4 b = *(const float4*)(x + i + 4);
  *(ushort4*)(Fbb + i) = make_ushort4(bfc(a.x), bfc(a.y), bfc(a.z), bfc(a.w));
  *(ushort4*)(Fbb + i + 4) = make_ushort4(bfc(b.x), bfc(b.y), bfc(b.z), bfc(b.w));
}

// ---------------------------------------------------------------------------
// k0b: transpose+cast. grid 4096.
// ---------------------------------------------------------------------------
__global__ __launch_bounds__(256) void cab_transpose(const float* __restrict__ x,
                                                     ushort* __restrict__ Ftb) {
  const int blk = blockIdx.x;
  const int b = blk & 7, seg = blk >> 3;
  const int d = seg >> 2, n0 = (seg & 3) * 1024;
  const float* F = x + (size_t)b * NT * DD;
  ushort* Ob = Ftb + (size_t)b * DD * NT;
  const int n = n0 + threadIdx.x * 4;
  ushort4 w;
  w.x = bfc(F[(size_t)(n + 0) * DD + d]);
  w.y = bfc(F[(size_t)(n + 1) * DD + d]);
  w.z = bfc(F[(size_t)(n + 2) * DD + d]);
  w.w = bfc(F[(size_t)(n + 3) * DD + d]);
  *(ushort4*)(Ob + (size_t)d * NT + n) = w;
}

// ---------------------------------------------------------------------------
// k0c: row norms of the bf16 data + per-batch max. grid 8 (1 block/batch).
// ---------------------------------------------------------------------------
__global__ __launch_bounds__(256) void cab_norms(const ushort* __restrict__ Fbb,
                                                 float* __restrict__ nrm,
                                                 float* __restrict__ mxf) {
  const int b = blockIdx.x;
  const ushort* Fb = Fbb + (size_t)b * NT * DD;
  __shared__ float red[256];
  const int t = threadIdx.x;
  float lmax = 0.f;
  for (int i = 0; i < 16; ++i) {
    int n = i * 256 + t;
    const ushort* row = Fb + (size_t)n * DD;
    float s = 0.f;
#pragma unroll
    for (int c = 0; c < 16; ++c) {
      bf16x8 v = *(const bf16x8*)(row + c * 8);
#pragma unroll
      for (int j = 0; j < 8; ++j) {
        float f = (float)v[j];
        s = fmaf(f, f, s);
      }
    }
    float r = sqrtf(s);
    nrm[(size_t)b * NT + n] = r;
    lmax = fmaxf(lmax, r);
  }
  red[t] = lmax;
  __syncthreads();
  for (int o = 128; o > 0; o >>= 1) {
    if (t < o) red[t] = fmaxf(red[t], red[t + o]);
    __syncthreads();
  }
  if (t == 0) mxf[b] = red[0];
}

// ---------------------------------------------------------------------------
// k1: Z partials. grid 1024: b=blk&7, nb=((blk>>3)&63)*64, mhalf=blk>>9.
// Wave (nh=wv>>1, mq=wv&1): A (32 n-rows) in regs; B from FmB; 1 barrier/step.
// ---------------------------------------------------------------------------
__global__ __launch_bounds__(256, 4) void cab_rowstats(const ushort* __restrict__ Fbb,
                                                       const float* __restrict__ nrm,
                                                       const float* __restrict__ mxf,
                                                       float* __restrict__ zpart) {
  const int b = blockIdx.x & 7;
  const int nb = ((blockIdx.x >> 3) & 63) * 64;
  const int mhalf = blockIdx.x >> 9;
  const ushort* Fb = Fbb + (size_t)b * NT * DD;

  const int t = threadIdx.x, lane = t & 63, wv = t >> 6;
  const int lcol = lane & 15, hi = lane >> 4;
  const int nh = wv >> 1, mq = wv & 1;

  __shared__ __align__(16) char FmB[2][16384];  // [64 m][16 chunks], swz ^(m&15)
  __shared__ float zred[64];

  // gload source offsets (element units): chunk L = i*256 + t
  int fmoff[4];
#pragma unroll
  for (int i = 0; i < 4; ++i) {
    int L = i * 256 + t;
    int m = L >> 4, c = (L & 15) ^ (m & 15);
    fmoff[i] = m * DD + c * 8;
  }

  // A fragments: wave's 32 n-rows, registers for whole kernel
  bf16x8 afr[2][4];
#pragma unroll
  for (int nt = 0; nt < 2; ++nt)
#pragma unroll
    for (int ks = 0; ks < 4; ++ks)
      afr[nt][ks] = *(const bf16x8*)(Fb + (size_t)(nb + nh * 32 + nt * 16 + lcol) * DD +
                                     ks * 32 + hi * 8);

  // per-row shift (Cauchy-Schwarz bound, log2 units), negated
  const float mxv = mxf[b] * L2E;
  float nsh[8];
#pragma unroll
  for (int nt = 0; nt < 2; ++nt)
#pragma unroll
    for (int r = 0; r < 4; ++r)
      nsh[nt * 4 + r] = -nrm[(size_t)b * NT + nb + nh * 32 + nt * 16 + hi * 4 + r] * mxv;

  const int mb0 = mhalf * 2048;
  // prologue: stage m-chunk 0
#pragma unroll
  for (int i = 0; i < 4; ++i)
    GLOAD16(Fb + (size_t)mb0 * DD + fmoff[i], &FmB[0][i * 4096 + wv * 1024]);
  __syncthreads();

  float zloc[8];
#pragma unroll
  for (int i = 0; i < 8; ++i) zloc[i] = 0.f;

  for (int s = 0; s < 32; ++s) {
    const int cur = s & 1;
    if (s < 31) {
      const ushort* src = Fb + (size_t)(mb0 + (s + 1) * 64) * DD;
#pragma unroll
      for (int i = 0; i < 4; ++i)
        GLOAD16(src + fmoff[i], &FmB[cur ^ 1][i * 4096 + wv * 1024]);
    }

    f32x4 sacc[2][2];  // [nt][msub]
#pragma unroll
    for (int nt = 0; nt < 2; ++nt)
#pragma unroll
      for (int ms = 0; ms < 2; ++ms) sacc[nt][ms] = (f32x4){0.f, 0.f, 0.f, 0.f};
#pragma unroll
    for (int ms = 0; ms < 2; ++ms)
#pragma unroll
      for (int ks = 0; ks < 4; ++ks) {
        int ml = mq * 32 + ms * 16 + lcol;
        bf16x8 bb = *(const bf16x8*)&FmB[cur][ml * 256 + (((ks * 4 + hi) ^ lcol) << 4)];
#pragma unroll
        for (int nt = 0; nt < 2; ++nt) sacc[nt][ms] = MFMA16(afr[nt][ks], bb, sacc[nt][ms]);
      }
#pragma unroll
    for (int nt = 0; nt < 2; ++nt)
#pragma unroll
      for (int r = 0; r < 4; ++r)
        zloc[nt * 4 + r] += __builtin_amdgcn_exp2f(fmaf(sacc[nt][0][r], L2E, nsh[nt * 4 + r])) +
                            __builtin_amdgcn_exp2f(fmaf(sacc[nt][1][r], L2E, nsh[nt * 4 + r]));
    __syncthreads();
  }

  // reduce over the 16 m-cols (lcol)
#pragma unroll
  for (int i = 0; i < 8; ++i) {
#pragma unroll
    for (int off = 1; off < 16; off <<= 1) zloc[i] += __shfl_xor(zloc[i], off, 64);
  }
  // cross-wave (mq) combine via LDS
  if (mq == 1 && lcol == 0) {
#pragma unroll
    for (int i = 0; i < 8; ++i) zred[nh * 32 + (i >> 2) * 16 + hi * 4 + (i & 3)] = zloc[i];
  }
  __syncthreads();
  if (mq == 0 && lcol == 0) {
#pragma unroll
    for (int i = 0; i < 8; ++i) {
      int nloc = nh * 32 + (i >> 2) * 16 + hi * 4 + (i & 3);
      zpart[(size_t)mhalf * 8 * NT + (size_t)b * NT + nb + nloc] = zloc[i] + zred[nloc];
    }
  }
}

// ---------------------------------------------------------------------------
// k1b: combine Z halves -> c2. grid 128.
// ---------------------------------------------------------------------------
__global__ __launch_bounds__(256) void cab_c2(const float* __restrict__ zpart,
                                              const float* __restrict__ nrm,
                                              const float* __restrict__ mxf,
                                              float* __restrict__ c2g) {
  int i = blockIdx.x * 256 + threadIdx.x;
  int b = i >> 12;
  float z = zpart[i] + zpart[8 * NT + i];
  float shift = nrm[i] * (mxf[b] * L2E);
  c2g[i] = -(shift + __log2f(z));
}

// ---------------------------------------------------------------------------
// k2: O = F^T W. grid 512: b=blk&7, mb0=(blk>>3)*64.
// Wave (mh=wv&1, nh=wv>>1): owns 32 m x 32 n per step; fmf in regs;
// W wave-private (no G1->G2 barrier); accO[128 d][32 m]; 1 barrier/step.
// Epilogue: nh-pairs sum accO via LDS, store f32.
// ---------------------------------------------------------------------------
__global__ __launch_bounds__(256, 2) void cab_out(const ushort* __restrict__ Fbb,
                                                  const ushort* __restrict__ Ftb,
                                                  const float* __restrict__ c2g,
                                                  float* __restrict__ out) {
  const int b = blockIdx.x & 7, mb0 = (blockIdx.x >> 3) * 64;
  const ushort* Fb = Fbb + (size_t)b * NT * DD;
  const ushort* Ft = Ftb + (size_t)b * DD * NT;
  const float* c2p = c2g + (size_t)b * NT;

  const int t = threadIdx.x, lane = t & 63, wv = t >> 6;
  const int lcol = lane & 15, hi = lane >> 4;
  const int mh = wv & 1, nh = wv >> 1;

  __shared__ __align__(16) char FnB[2][16384];   // [64 n][16 chunks], swz ^(n&15)
  __shared__ __align__(16) char FttB[2][16384];  // [128 d][8 chunks], swz ^(d&7)
  __shared__ __align__(16) char Wt[9216];        // 4 x [32 m][72 B] wave-private
  __shared__ __align__(16) float c2l[2][64];

  // gload source offsets
  int fnoff[4], fttoff[4];
#pragma unroll
  for (int i = 0; i < 4; ++i) {
    int L = i * 256 + t;
    int n = L >> 4, cn = (L & 15) ^ (n & 15);
    fnoff[i] = n * DD + cn * 8;
    int d = L >> 3, cd = (L & 7) ^ (d & 7);
    fttoff[i] = d * NT + cd * 8;
  }

  // G1 B-operand: wave's 32 m-rows in registers
  bf16x8 fmf[2][4];
#pragma unroll
  for (int ms = 0; ms < 2; ++ms)
#pragma unroll
    for (int ks = 0; ks < 4; ++ks)
      fmf[ms][ks] = *(const bf16x8*)(Fb + (size_t)(mb0 + mh * 32 + ms * 16 + lcol) * DD +
                                     ks * 32 + hi * 8);

  f32x4 accO[8][2];  // [dt][msub]
#pragma unroll
  for (int dt = 0; dt < 8; ++dt)
#pragma unroll
    for (int ms = 0; ms < 2; ++ms) accO[dt][ms] = (f32x4){0.f, 0.f, 0.f, 0.f};

  // prologue: stage step 0
#pragma unroll
  for (int i = 0; i < 4; ++i) GLOAD16(Fb + fnoff[i], &FnB[0][i * 4096 + wv * 1024]);
#pragma unroll
  for (int i = 0; i < 4; ++i) GLOAD16(Ft + fttoff[i], &FttB[0][i * 4096 + wv * 1024]);
  if (wv == 0) GLOAD4(c2p + lane, &c2l[0][0]);
  __syncthreads();

  const unsigned wtbase = wv * 2304;

  for (int s = 0; s < 64; ++s) {
    const int cur = s & 1;
    if (s < 63) {
      const ushort* fs = Fb + (size_t)(s + 1) * 64 * DD;
      const ushort* ts = Ft + (s + 1) * 64;
#pragma unroll
      for (int i = 0; i < 4; ++i)
        GLOAD16(fs + fnoff[i], &FnB[cur ^ 1][i * 4096 + wv * 1024]);
#pragma unroll
      for (int i = 0; i < 4; ++i)
        GLOAD16(ts + fttoff[i], &FttB[cur ^ 1][i * 4096 + wv * 1024]);
      if (wv == 0) GLOAD4(c2p + (s + 1) * 64 + lane, &c2l[cur ^ 1][0]);
    }

    // G1: S[wave's 32 n][wave's 32 m]; chain identical to k1 -> same S
    f32x4 sacc[2][2];  // [nt][msub]
#pragma unroll
    for (int nt = 0; nt < 2; ++nt)
#pragma unroll
      for (int ms = 0; ms < 2; ++ms) sacc[nt][ms] = (f32x4){0.f, 0.f, 0.f, 0.f};
#pragma unroll
    for (int nt = 0; nt < 2; ++nt)
#pragma unroll
      for (int ks = 0; ks < 4; ++ks) {
        int n = (nh * 2 + nt) * 16 + lcol;
        bf16x8 a = *(const bf16x8*)&FnB[cur][n * 256 + (((ks * 4 + hi) ^ lcol) << 4)];
#pragma unroll
        for (int ms = 0; ms < 2; ++ms) sacc[nt][ms] = MFMA16(a, fmf[ms][ks], sacc[nt][ms]);
      }

    // W = 2^(S*L2E + c2) -> wave-private Wt [32 m][72 B rows]
#pragma unroll
    for (int nt = 0; nt < 2; ++nt) {
      float4 cv = *(const float4*)&c2l[cur][nh * 32 + nt * 16 + hi * 4];
#pragma unroll
      for (int ms = 0; ms < 2; ++ms) {
        ushort4 wp;
        wp.x = bfc(__builtin_amdgcn_exp2f(fmaf(sacc[nt][ms][0], L2E, cv.x)));
        wp.y = bfc(__builtin_amdgcn_exp2f(fmaf(sacc[nt][ms][1], L2E, cv.y)));
        wp.z = bfc(__builtin_amdgcn_exp2f(fmaf(sacc[nt][ms][2], L2E, cv.z)));
        wp.w = bfc(__builtin_amdgcn_exp2f(fmaf(sacc[nt][ms][3], L2E, cv.w)));
        *(ushort4*)&Wt[wtbase + (ms * 16 + lcol) * 72 + nt * 32 + hi * 8] = wp;
      }
    }

    // G2: accO[dt][ms] += Ftt[d][wave's 32 n] x W  (same-wave LDS dep only)
    bf16x8 b2[2];
#pragma unroll
    for (int ms = 0; ms < 2; ++ms) {
      const char* p = &Wt[wtbase + (ms * 16 + lcol) * 72 + hi * 16];
      uint2 lo = *(const uint2*)p;
      uint2 h2 = *(const uint2*)(p + 8);
      b2[ms] = __builtin_bit_cast(bf16x8, (u32x4){lo.x, lo.y, h2.x, h2.y});
    }
#pragma unroll
    for (int dt = 0; dt < 8; ++dt) {
      bf16x8 a2 = *(const bf16x8*)&FttB[cur][(dt * 16 + lcol) * 128 +
                                            (((nh * 4 + hi) ^ (lcol & 7)) << 4)];
#pragma unroll
      for (int ms = 0; ms < 2; ++ms) accO[dt][ms] = MFMA16(a2, b2[ms], accO[dt][ms]);
    }

    __syncthreads();  // drain gloads, flip buffers (only barrier in the step)
  }

  // epilogue: sum nh-partials via LDS, store
  float* red = (float*)&FnB[0][0];  // 32 KB scratch
  if (nh == 1) {
#pragma unroll
    for (int dt = 0; dt < 8; ++dt)
#pragma unroll
      for (int ms = 0; ms < 2; ++ms)
#pragma unroll
        for (int r = 0; r < 4; ++r)
          red[mh * 4096 + (dt * 8 + ms * 4 + r) * 64 + lane] = accO[dt][ms][r];
  }
  __syncthreads();
  if (nh == 0) {
    float* Ob = out + (size_t)b * DD * NT;
#pragma unroll
    for (int dt = 0; dt < 8; ++dt)
#pragma unroll
      for (int ms = 0; ms < 2; ++ms)
#pragma unroll
        for (int r = 0; r < 4; ++r) {
          float v = accO[dt][ms][r] + red[mh * 4096 + (dt * 8 + ms * 4 + r) * 64 + lane];
          Ob[(size_t)(dt * 16 + hi * 4 + r) * NT + mb0 + mh * 32 + ms * 16 + lcol] = v;
        }
  }
}

extern "C" void kernel_launch(void* const* d_in, const int* in_sizes, int n_in,
                              void* d_out, int out_size, void* d_ws, size_t ws_size,
                              hipStream_t stream) {
  const float* x = (const float*)d_in[0];
  float* out = (float*)d_out;
  char* ws = (char*)d_ws;
  ushort* Fbb = (ushort*)ws;                       // 8 MB
  ushort* Ftb = (ushort*)(ws + (8u << 20));        // 8 MB
  float* nrm = (float*)(ws + (16u << 20));         // 128 KB
  float* mxf = (float*)(ws + (16u << 20) + 131072);        // 32 B (padded 1 KB)
  float* zpart = (float*)(ws + (16u << 20) + 132096);      // 256 KB
  float* c2 = (float*)(ws + (16u << 20) + 132096 + 262144);  // 128 KB

  hipLaunchKernelGGL(cab_cast, dim3(2048), dim3(256), 0, stream, x, Fbb);
  hipLaunchKernelGGL(cab_transpose, dim3(4096), dim3(256), 0, stream, x, Ftb);
  hipLaunchKernelGGL(cab_norms, dim3(8), dim3(256), 0, stream, Fbb, nrm, mxf);
  hipLaunchKernelGGL(cab_rowstats, dim3(1024), dim3(256), 0, stream, Fbb, nrm, mxf, zpart);
  hipLaunchKernelGGL(cab_c2, dim3(128), dim3(256), 0, stream, zpart, nrm, mxf, c2);
  hipLaunchKernelGGL(cab_out, dim3(512), dim3(256), 0, stream, Fbb, Ftb, c2, out);
}